// Round 1
// baseline (193.972 us; speedup 1.0000x reference)
//
#include <hip/hip_runtime.h>
#include <stdint.h>
#include <math.h>

typedef unsigned long long u64;
typedef uint32_t u32;

#define BATCH   262144
#define DIM     120
#define NBLK1   2048      // K1/K2: 128 rows per block
#define NPART   4096      // partial slots per column (2 halves * 2048 blocks)

// ---------------- workspace layout (bytes) ----------------
#define WS_XBITS   0              // u64[BATCH*4]            8,388,608
#define WS_WBITS   8388608        // u64[128*4]                  4,096
#define WS_HS      8392704        // u32[120*4096]           1,966,080
#define WS_HS2     10358784       // u32[120*4096]           1,966,080
#define WS_SS      12324864       // f32[120*4096]           1,966,080
#define WS_SS2     14290944       // f32[120*4096]           1,966,080
#define WS_BN2C    16257024       // f32[256]  (c1q[j], c0[128+j])
#define WS_BN1C    16258048       // f32[256]  (d1[j], d0[128+j])
#define WS_OQ      16259072       // u32[BATCH]              1,048,576
#define WS_OACC    17307648       // u32 oS[2]; pad; u64 oS2[2]@+16; f32 fin[4]@+32
#define WS_TOTAL   17307712

// Pack conv_w: bit for column c goes to word (c&1), position (c>>1)
// (permuted order — matches the float2-ballot packing of x; popcounts are
// invariant under a common bit permutation).
__global__ void kw_pack(const float* __restrict__ w, u64* __restrict__ wbits) {
    int j = threadIdx.x;
    if (j >= 128) return;
    u64 q0 = 0, q1 = 0, y0 = 0, y1 = 0;
    if (j < DIM) {
        const float* row = w + j * DIM;
        for (int c = 0; c < DIM; ++c) {
            float v = row[c];
            u64 bit = 1ull << (c >> 1);
            if (v > 0.f)       { if (c & 1) q1 |= bit; else q0 |= bit; }
            else if (v == 0.f) { if (c & 1) y1 |= bit; else y0 |= bit; }
        }
    }
    wbits[j*4+0] = q0; wbits[j*4+1] = q1; wbits[j*4+2] = y0; wbits[j*4+3] = y1;
}

__device__ __forceinline__ u32 hq_from_bits(u64 p0, u64 p1, u64 z0, u64 z1,
                                            u64 q0, u64 q1, u64 y0, u64 y1,
                                            bool hasY) {
    u32 hq = (u32)(__popcll(p0 & q0) + __popcll(p1 & q1)) << 2;
    if (hasY)
        hq += 2u * (u32)(__popcll(p0 & y0) + __popcll(p1 & y1))
            + (u32)(__popcll(z0 & y0) + __popcll(z1 & y1));
    if (z0 | z1)
        hq += 2u * (u32)(__popcll(z0 & q0) + __popcll(z1 & q1));
    return hq;   // == 4 * h, exact integer in [0, 480]
}

// K1: pack x into bits (ballot), store bits to global, compute integer
// per-column sums of hq and hq^2 (exact, deterministic).
__global__ __launch_bounds__(256) void k1_pack_hstats(
        const float* __restrict__ x, const u64* __restrict__ wbits,
        u64* __restrict__ xbits, u32* __restrict__ hS, u32* __restrict__ hS2) {
    __shared__ u64 lb[128][4];
    int tid = threadIdx.x, lane = tid & 63, wave = tid >> 6;
    size_t rowbase = (size_t)blockIdx.x * 128;

    // phase A: 4 waves x 32 rows; one float2 load covers a whole 120-col row
    for (int rr = 0; rr < 32; ++rr) {
        int r = wave * 32 + rr;
        float2 v = make_float2(-1.f, -1.f);
        if (lane < 60) v = *(const float2*)(x + (rowbase + r) * (size_t)DIM + lane * 2);
        u64 pe = __ballot(v.x > 0.f);
        u64 po = __ballot(v.y > 0.f);
        u64 ze = __ballot(v.x == 0.f);
        u64 zo = __ballot(v.y == 0.f);
        if (lane == 0) { lb[r][0] = pe; lb[r][1] = po; lb[r][2] = ze; lb[r][3] = zo; }
    }
    __syncthreads();
    {   // coalesced copy of packed bits to global for later passes
        u64* dst = xbits + (size_t)blockIdx.x * 512;
        const u64* src = &lb[0][0];
        for (int k = tid; k < 512; k += 256) dst[k] = src[k];
    }
    // phase B: thread <-> column; integer stats in registers
    int j = tid & 127, half = tid >> 7;
    if (j < DIM) {
        u64 q0 = wbits[j*4+0], q1 = wbits[j*4+1], y0 = wbits[j*4+2], y1 = wbits[j*4+3];
        bool hasY = (y0 | y1) != 0;
        u32 S = 0, S2 = 0;
        int r0 = half * 64;
        for (int r = r0; r < r0 + 64; ++r) {
            u32 hq = hq_from_bits(lb[r][0], lb[r][1], lb[r][2], lb[r][3],
                                  q0, q1, y0, y1, hasY);
            S += hq; S2 += hq * hq;
        }
        int pidx = j * NPART + blockIdx.x * 2 + half;
        hS[pidx] = S; hS2[pidx] = S2;
    }
}

// R1: reduce integer h-stats -> fold BN2 into  z = fma(hq, c1q, c0)
__global__ __launch_bounds__(256) void r1_hreduce(
        const u32* __restrict__ hS, const u32* __restrict__ hS2,
        const float* __restrict__ g2, const float* __restrict__ b2,
        float* __restrict__ bn2c) {
    int j = blockIdx.x, tid = threadIdx.x;
    u32 s = 0; u64 s2 = 0;
    for (int k = tid; k < NPART; k += 256) { s += hS[j*NPART+k]; s2 += (u64)hS2[j*NPART+k]; }
    for (int off = 32; off; off >>= 1) { s += __shfl_down(s, off, 64); s2 += __shfl_down(s2, off, 64); }
    __shared__ u32 as_[4]; __shared__ u64 as2_[4];
    int lane = tid & 63, wave = tid >> 6;
    if (lane == 0) { as_[wave] = s; as2_[wave] = s2; }
    __syncthreads();
    if (tid == 0) {
        u32 S = as_[0] + as_[1] + as_[2] + as_[3];
        u64 S2 = as2_[0] + as2_[1] + as2_[2] + as2_[3];
        double m2 = (double)S * 0.25 / (double)BATCH;
        double e2 = (double)S2 * 0.0625 / (double)BATCH;
        double v2 = e2 - m2 * m2;
        float rs = (float)(1.0 / sqrt(v2 + 1e-5));
        float c1 = rs * g2[j];
        float c0 = fmaf(-(float)m2, c1, b2[j]);
        bn2c[j]       = c1 * 0.25f;   // pre-scaled for hq (=4h)
        bn2c[128 + j] = c0;
    }
}

// K2: recompute hq from bits, softsign stats (f32 partials, fixed order)
__global__ __launch_bounds__(256) void k2_sstats(
        const u64* __restrict__ xbits, const u64* __restrict__ wbits,
        const float* __restrict__ bn2c,
        float* __restrict__ sS, float* __restrict__ sS2) {
    int tid = threadIdx.x, j = tid & 127, half = tid >> 7;
    if (j >= DIM) return;
    u64 q0 = wbits[j*4+0], q1 = wbits[j*4+1], y0 = wbits[j*4+2], y1 = wbits[j*4+3];
    bool hasY = (y0 | y1) != 0;
    float c1q = bn2c[j], c0 = bn2c[128 + j];
    float Ss = 0.f, Ss2 = 0.f;
    size_t base = (size_t)blockIdx.x * 128 + (size_t)half * 64;
    const u64* rb = xbits + base * 4;
    for (int r = 0; r < 64; ++r) {
        u64 p0 = rb[r*4+0], p1 = rb[r*4+1], z0 = rb[r*4+2], z1 = rb[r*4+3];
        u32 hq = hq_from_bits(p0, p1, z0, z1, q0, q1, y0, y1, hasY);
        float z = fmaf((float)hq, c1q, c0);
        float s = z * __builtin_amdgcn_rcpf(1.f + fabsf(z));
        Ss += s; Ss2 = fmaf(s, s, Ss2);
    }
    int pidx = j * NPART + blockIdx.x * 2 + half;
    sS[pidx] = Ss; sS2[pidx] = Ss2;
}

// R2: reduce softsign stats (f64 accumulation) -> fold BN1: h1 = fma(s, d1, d0)
__global__ __launch_bounds__(256) void r2_sreduce(
        const float* __restrict__ sS, const float* __restrict__ sS2,
        const float* __restrict__ g1, const float* __restrict__ b1,
        float* __restrict__ bn1c) {
    int j = blockIdx.x, tid = threadIdx.x;
    double s = 0.0, s2 = 0.0;
    for (int k = tid; k < NPART; k += 256) { s += (double)sS[j*NPART+k]; s2 += (double)sS2[j*NPART+k]; }
    for (int off = 32; off; off >>= 1) { s += __shfl_down(s, off, 64); s2 += __shfl_down(s2, off, 64); }
    __shared__ double ds_[4], ds2_[4];
    int lane = tid & 63, wave = tid >> 6;
    if (lane == 0) { ds_[wave] = s; ds2_[wave] = s2; }
    __syncthreads();
    if (tid == 0) {
        double S = ds_[0] + ds_[1] + ds_[2] + ds_[3];
        double S2 = ds2_[0] + ds2_[1] + ds2_[2] + ds2_[3];
        double m1 = S / (double)BATCH;
        double v1 = S2 / (double)BATCH - m1 * m1;
        float rs = (float)(1.0 / sqrt(v1 + 1e-5));
        float d1 = rs * g1[j];
        float d0 = fmaf(-(float)m1, d1, b1[j]);
        bn1c[j]       = d1;
        bn1c[128 + j] = d0;
    }
}

// K3: thread <-> row; recompute hq, softsign, binarize, tiny 120x2 matvec,
// exact integer out-stats via block-reduced global atomics, store oq packed.
__global__ __launch_bounds__(256) void k3_out(
        const u64* __restrict__ xbits, const u64* __restrict__ wbits,
        const float* __restrict__ bn2c, const float* __restrict__ bn1c,
        const float* __restrict__ lw, u32* __restrict__ oqbuf,
        u32* __restrict__ oS, u64* __restrict__ oS2) {
    __shared__ float4 sc[128];
    __shared__ u32 slw[128];
    __shared__ u64 sqy[128][4];
    int tid = threadIdx.x;
    if (tid < DIM) {
        sc[tid] = make_float4(bn2c[tid], bn2c[128 + tid], bn1c[tid], bn1c[128 + tid]);
        float w0 = lw[tid], w1 = lw[DIM + tid];
        u32 l0 = w0 > 0.f ? 2u : (w0 == 0.f ? 1u : 0u);
        u32 l1 = w1 > 0.f ? 2u : (w1 == 0.f ? 1u : 0u);
        slw[tid] = l0 | (l1 << 16);
        sqy[tid][0] = wbits[tid*4+0]; sqy[tid][1] = wbits[tid*4+1];
        sqy[tid][2] = wbits[tid*4+2]; sqy[tid][3] = wbits[tid*4+3];
    }
    __syncthreads();
    size_t row = (size_t)blockIdx.x * 256 + tid;
    const u64* rb = xbits + row * 4;
    u64 p0 = rb[0], p1 = rb[1], z0 = rb[2], z1 = rb[3];
    u32 oq0 = 0, oq1 = 0;
    for (int j = 0; j < DIM; ++j) {
        u64 q0 = sqy[j][0], q1 = sqy[j][1], y0 = sqy[j][2], y1 = sqy[j][3];
        bool hasY = (y0 | y1) != 0;           // j is wave-uniform
        u32 hq = hq_from_bits(p0, p1, z0, z1, q0, q1, y0, y1, hasY);
        float4 c = sc[j];
        float z = fmaf((float)hq, c.x, c.y);
        float s = z * __builtin_amdgcn_rcpf(1.f + fabsf(z));
        float h1 = fmaf(s, c.z, c.w);
        u32 hb2 = h1 > 0.f ? 2u : (h1 == 0.f ? 1u : 0u);   // 2*binarize
        u32 lwp = slw[j];
        oq0 += hb2 * (lwp & 0xffffu);   // oq = 4 * out (exact integer)
        oq1 += hb2 * (lwp >> 16);
    }
    oqbuf[row] = oq0 | (oq1 << 16);
    u32 a = oq0, b = oq1, c2 = oq0 * oq0, d2 = oq1 * oq1;
    for (int off = 32; off; off >>= 1) {
        a += __shfl_down(a, off, 64);  b += __shfl_down(b, off, 64);
        c2 += __shfl_down(c2, off, 64); d2 += __shfl_down(d2, off, 64);
    }
    __shared__ u32 r0_[4], r1_[4], r2_[4], r3_[4];
    int lane = tid & 63, wave = tid >> 6;
    if (lane == 0) { r0_[wave] = a; r1_[wave] = b; r2_[wave] = c2; r3_[wave] = d2; }
    __syncthreads();
    if (tid == 0) {
        atomicAdd(&oS[0], r0_[0] + r0_[1] + r0_[2] + r0_[3]);
        atomicAdd(&oS[1], r1_[0] + r1_[1] + r1_[2] + r1_[3]);
        atomicAdd(&oS2[0], (u64)(r2_[0] + r2_[1] + r2_[2] + r2_[3]));
        atomicAdd(&oS2[1], (u64)(r3_[0] + r3_[1] + r3_[2] + r3_[3]));
    }
}

// R3: finalize output BN constants (lin_b cancels through the no-affine BN)
__global__ void r3_ostats(const u32* __restrict__ oS, const u64* __restrict__ oS2,
                          float* __restrict__ fin) {
    if (threadIdx.x == 0) {
        for (int c = 0; c < 2; ++c) {
            double a  = (double)oS[c] * 0.25 / (double)BATCH;
            double e2 = (double)oS2[c] * 0.0625 / (double)BATCH;
            double vo = e2 - a * a;
            fin[c]     = (float)a;
            fin[2 + c] = (float)(1.0 / sqrt(vo + 1e-5));
        }
    }
}

// K4: normalize + 2-class log_softmax
__global__ __launch_bounds__(256) void k4_final(
        const u32* __restrict__ oqbuf, const float* __restrict__ fin,
        float* __restrict__ out) {
    size_t row = (size_t)blockIdx.x * 256 + threadIdx.x;
    u32 v = oqbuf[row];
    float o0 = ((float)(v & 0xffffu) * 0.25f - fin[0]) * fin[2];
    float o1 = ((float)(v >> 16)     * 0.25f - fin[1]) * fin[3];
    float m = fmaxf(o0, o1);
    float l0 = o0 - m, l1 = o1 - m;
    float ls = logf(expf(l0) + expf(l1));
    ((float2*)out)[row] = make_float2(l0 - ls, l1 - ls);
}

extern "C" void kernel_launch(void* const* d_in, const int* in_sizes, int n_in,
                              void* d_out, int out_size, void* d_ws, size_t ws_size,
                              hipStream_t stream) {
    const float* x  = (const float*)d_in[0];
    const float* cw = (const float*)d_in[1];
    const float* g2 = (const float*)d_in[2];
    const float* b2 = (const float*)d_in[3];
    const float* g1 = (const float*)d_in[4];
    const float* b1 = (const float*)d_in[5];
    const float* lw = (const float*)d_in[6];
    // d_in[7] (lin_b) cancels through the final no-affine batchnorm
    float* out = (float*)d_out;
    if (ws_size < (size_t)WS_TOTAL) return;   // fail loudly via poisoned d_out

    char* ws = (char*)d_ws;
    u64* xbits = (u64*)(ws + WS_XBITS);
    u64* wbits = (u64*)(ws + WS_WBITS);
    u32* hS    = (u32*)(ws + WS_HS);
    u32* hS2   = (u32*)(ws + WS_HS2);
    float* sS  = (float*)(ws + WS_SS);
    float* sS2 = (float*)(ws + WS_SS2);
    float* bn2c = (float*)(ws + WS_BN2C);
    float* bn1c = (float*)(ws + WS_BN1C);
    u32* oqbuf = (u32*)(ws + WS_OQ);
    u32* oS    = (u32*)(ws + WS_OACC);
    u64* oS2   = (u64*)(ws + WS_OACC + 16);
    float* fin = (float*)(ws + WS_OACC + 32);

    hipMemsetAsync(ws + WS_OACC, 0, 32, stream);
    kw_pack      <<<1, 128, 0, stream>>>(cw, wbits);
    k1_pack_hstats<<<NBLK1, 256, 0, stream>>>(x, wbits, xbits, hS, hS2);
    r1_hreduce   <<<DIM, 256, 0, stream>>>(hS, hS2, g2, b2, bn2c);
    k2_sstats    <<<NBLK1, 256, 0, stream>>>(xbits, wbits, bn2c, sS, sS2);
    r2_sreduce   <<<DIM, 256, 0, stream>>>(sS, sS2, g1, b1, bn1c);
    k3_out       <<<BATCH/256, 256, 0, stream>>>(xbits, wbits, bn2c, bn1c, lw, oqbuf, oS, oS2);
    r3_ostats    <<<1, 64, 0, stream>>>(oS, oS2, fin);
    k4_final     <<<BATCH/256, 256, 0, stream>>>(oqbuf, fin, out);
}

// Round 2
// 183.027 us; speedup vs baseline: 1.0598x; 1.0598x over previous
//
#include <hip/hip_runtime.h>
#include <stdint.h>
#include <math.h>

typedef unsigned long long u64;
typedef uint32_t u32;

#define BATCH   262144
#define DIM     120
#define NBLK1   2048      // K1/K2: 128 rows per block
#define NPART   4096      // partial slots per column (2 halves * 2048 blocks)
#define K3R     2         // rows per thread in k3

// ---------------- workspace layout (bytes) ----------------
#define WS_XBITS   0              // u64[BATCH*4]            8,388,608
#define WS_WBITS   8388608        // u64[128*4]                  4,096
#define WS_HS      8392704        // u32[120*4096]           1,966,080
#define WS_HS2     10358784       // u32[120*4096]           1,966,080
#define WS_SS      12324864       // f32[120*4096]           1,966,080
#define WS_SS2     14290944       // f32[120*4096]           1,966,080
#define WS_BN2C    16257024       // f32[256]  (c1q[j], c0[128+j])
#define WS_LWQ     16258048       // u32[128]  packed lin_w binarize
#define WS_TAB     16258560       // u32[120*32] 2-bit hb2 LUT      15,360
#define WS_OQ      16273920       // u32[BATCH]              1,048,576
#define WS_OACC    17322496       // u32 oS[2]; pad; u64 oS2[2]@+16; f32 fin[4]@+32
#define WS_TOTAL   17322560

// Pack conv_w: bit for column c goes to word (c&1), position (c>>1)
// (permuted order — matches the float2-ballot packing of x; popcounts are
// invariant under a common bit permutation). Also packs lin_w binarize and
// zeroes the k3 output accumulators (replaces the 72us hipMemsetAsync!).
__global__ void kw_pack(const float* __restrict__ w, const float* __restrict__ lw,
                        u64* __restrict__ wbits, u32* __restrict__ lwq,
                        u32* __restrict__ oaccz) {
    int j = threadIdx.x;
    if (j >= 128) return;
    if (j < 8) oaccz[j] = 0;              // zero oS[2] + pad + oS2[2]
    u64 q0 = 0, q1 = 0, y0 = 0, y1 = 0;
    u32 lwp = 0;
    if (j < DIM) {
        const float* row = w + j * DIM;
        for (int c = 0; c < DIM; ++c) {
            float v = row[c];
            u64 bit = 1ull << (c >> 1);
            if (v > 0.f)       { if (c & 1) q1 |= bit; else q0 |= bit; }
            else if (v == 0.f) { if (c & 1) y1 |= bit; else y0 |= bit; }
        }
        float w0 = lw[j], w1 = lw[DIM + j];
        u32 l0 = w0 > 0.f ? 2u : (w0 == 0.f ? 1u : 0u);
        u32 l1 = w1 > 0.f ? 2u : (w1 == 0.f ? 1u : 0u);
        lwp = l0 | (l1 << 16);
    }
    wbits[j*4+0] = q0; wbits[j*4+1] = q1; wbits[j*4+2] = y0; wbits[j*4+3] = y1;
    lwq[j] = lwp;
}

__device__ __forceinline__ u32 hq_from_bits(u64 p0, u64 p1, u64 z0, u64 z1,
                                            u64 q0, u64 q1, u64 y0, u64 y1,
                                            bool hasY, bool hasZ) {
    u32 hq = (u32)(__popcll(p0 & q0) + __popcll(p1 & q1)) << 2;
    if (hasY)
        hq += 2u * (u32)(__popcll(p0 & y0) + __popcll(p1 & y1))
            + (u32)(__popcll(z0 & y0) + __popcll(z1 & y1));
    if (hasZ)
        hq += 2u * (u32)(__popcll(z0 & q0) + __popcll(z1 & q1));
    return hq;   // == 4 * h, exact integer in [0, 480]
}

// K1: pack x into bits (ballot), store bits to global, compute integer
// per-column sums of hq and hq^2 (exact, deterministic).
__global__ __launch_bounds__(256) void k1_pack_hstats(
        const float* __restrict__ x, const u64* __restrict__ wbits,
        u64* __restrict__ xbits, u32* __restrict__ hS, u32* __restrict__ hS2) {
    __shared__ u64 lb[128][4];
    int tid = threadIdx.x, lane = tid & 63, wave = tid >> 6;
    size_t rowbase = (size_t)blockIdx.x * 128;

    // phase A: 4 waves x 32 rows; one float2 load covers a whole 120-col row
    for (int rr = 0; rr < 32; ++rr) {
        int r = wave * 32 + rr;
        float2 v = make_float2(-1.f, -1.f);
        if (lane < 60) v = *(const float2*)(x + (rowbase + r) * (size_t)DIM + lane * 2);
        u64 pe = __ballot(v.x > 0.f);
        u64 po = __ballot(v.y > 0.f);
        u64 ze = __ballot(v.x == 0.f);
        u64 zo = __ballot(v.y == 0.f);
        if (lane == 0) { lb[r][0] = pe; lb[r][1] = po; lb[r][2] = ze; lb[r][3] = zo; }
    }
    __syncthreads();
    {   // coalesced copy of packed bits to global for later passes
        u64* dst = xbits + (size_t)blockIdx.x * 512;
        const u64* src = &lb[0][0];
        for (int k = tid; k < 512; k += 256) dst[k] = src[k];
    }
    // phase B: thread <-> column; integer stats in registers
    int j = tid & 127, half = tid >> 7;
    if (j < DIM) {
        u64 q0 = wbits[j*4+0], q1 = wbits[j*4+1], y0 = wbits[j*4+2], y1 = wbits[j*4+3];
        bool hasY = (y0 | y1) != 0;
        u32 S = 0, S2 = 0;
        int r0 = half * 64;
        for (int r = r0; r < r0 + 64; ++r) {
            u64 z0 = lb[r][2], z1 = lb[r][3];
            u32 hq = hq_from_bits(lb[r][0], lb[r][1], z0, z1,
                                  q0, q1, y0, y1, hasY, (z0 | z1) != 0);
            S += hq; S2 += hq * hq;
        }
        int pidx = j * NPART + blockIdx.x * 2 + half;
        hS[pidx] = S; hS2[pidx] = S2;
    }
}

// R1: reduce integer h-stats -> fold BN2 into  z = fma(hq, c1q, c0)
__global__ __launch_bounds__(256) void r1_hreduce(
        const u32* __restrict__ hS, const u32* __restrict__ hS2,
        const float* __restrict__ g2, const float* __restrict__ b2,
        float* __restrict__ bn2c) {
    int j = blockIdx.x, tid = threadIdx.x;
    u32 s = 0; u64 s2 = 0;
    for (int k = tid; k < NPART; k += 256) { s += hS[j*NPART+k]; s2 += (u64)hS2[j*NPART+k]; }
    for (int off = 32; off; off >>= 1) { s += __shfl_down(s, off, 64); s2 += __shfl_down(s2, off, 64); }
    __shared__ u32 as_[4]; __shared__ u64 as2_[4];
    int lane = tid & 63, wave = tid >> 6;
    if (lane == 0) { as_[wave] = s; as2_[wave] = s2; }
    __syncthreads();
    if (tid == 0) {
        u32 S = as_[0] + as_[1] + as_[2] + as_[3];
        u64 S2 = as2_[0] + as2_[1] + as2_[2] + as2_[3];
        double m2 = (double)S * 0.25 / (double)BATCH;
        double e2 = (double)S2 * 0.0625 / (double)BATCH;
        double v2 = e2 - m2 * m2;
        float rs = (float)(1.0 / sqrt(v2 + 1e-5));
        float c1 = rs * g2[j];
        float c0 = fmaf(-(float)m2, c1, b2[j]);
        bn2c[j]       = c1 * 0.25f;   // pre-scaled for hq (=4h)
        bn2c[128 + j] = c0;
    }
}

// K2: recompute hq from bits, softsign stats (f32 partials, fixed order)
__global__ __launch_bounds__(256) void k2_sstats(
        const u64* __restrict__ xbits, const u64* __restrict__ wbits,
        const float* __restrict__ bn2c,
        float* __restrict__ sS, float* __restrict__ sS2) {
    int tid = threadIdx.x, j = tid & 127, half = tid >> 7;
    if (j >= DIM) return;
    u64 q0 = wbits[j*4+0], q1 = wbits[j*4+1], y0 = wbits[j*4+2], y1 = wbits[j*4+3];
    bool hasY = (y0 | y1) != 0;
    float c1q = bn2c[j], c0 = bn2c[128 + j];
    float Ss = 0.f, Ss2 = 0.f;
    size_t base = (size_t)blockIdx.x * 128 + (size_t)half * 64;
    const u64* rb = xbits + base * 4;
    for (int r = 0; r < 64; ++r) {
        u64 p0 = rb[r*4+0], p1 = rb[r*4+1], z0 = rb[r*4+2], z1 = rb[r*4+3];
        u32 hq = hq_from_bits(p0, p1, z0, z1, q0, q1, y0, y1, hasY, (z0 | z1) != 0);
        float z = fmaf((float)hq, c1q, c0);
        float s = z * __builtin_amdgcn_rcpf(1.f + fabsf(z));
        Ss += s; Ss2 = fmaf(s, s, Ss2);
    }
    int pidx = j * NPART + blockIdx.x * 2 + half;
    sS[pidx] = Ss; sS2[pidx] = Ss2;
}

// R2: reduce softsign stats (f64 accumulation), fold BN1, then build the
// per-column 2-bit binarize LUT over all 481 possible hq values using the
// EXACT float instruction sequence k3 previously used (incl. rcpf) — so the
// decisions are bit-identical to the passing per-element version.
__global__ __launch_bounds__(256) void r2_sreduce(
        const float* __restrict__ sS, const float* __restrict__ sS2,
        const float* __restrict__ g1, const float* __restrict__ b1,
        const float* __restrict__ bn2c, u32* __restrict__ tab) {
    int j = blockIdx.x, tid = threadIdx.x;
    double s = 0.0, s2 = 0.0;
    for (int k = tid; k < NPART; k += 256) { s += (double)sS[j*NPART+k]; s2 += (double)sS2[j*NPART+k]; }
    for (int off = 32; off; off >>= 1) { s += __shfl_down(s, off, 64); s2 += __shfl_down(s2, off, 64); }
    __shared__ double ds_[4], ds2_[4];
    __shared__ float sd1, sd0;
    __shared__ u32 tw[32];
    int lane = tid & 63, wave = tid >> 6;
    if (lane == 0) { ds_[wave] = s; ds2_[wave] = s2; }
    if (tid < 32) tw[tid] = 0;
    __syncthreads();
    if (tid == 0) {
        double S = ds_[0] + ds_[1] + ds_[2] + ds_[3];
        double S2 = ds2_[0] + ds2_[1] + ds2_[2] + ds2_[3];
        double m1 = S / (double)BATCH;
        double v1 = S2 / (double)BATCH - m1 * m1;
        float rs = (float)(1.0 / sqrt(v1 + 1e-5));
        float d1 = rs * g1[j];
        float d0 = fmaf(-(float)m1, d1, b1[j]);
        sd1 = d1; sd0 = d0;
    }
    __syncthreads();
    float c1q = bn2c[j], c0 = bn2c[128 + j];
    float d1 = sd1, d0 = sd0;
    for (int hq = tid; hq < 481; hq += 256) {
        float z = fmaf((float)hq, c1q, c0);
        float sv = z * __builtin_amdgcn_rcpf(1.f + fabsf(z));
        float h1 = fmaf(sv, d1, d0);
        u32 hb2 = h1 > 0.f ? 2u : (h1 == 0.f ? 1u : 0u);
        atomicOr(&tw[hq >> 4], hb2 << ((hq & 15) * 2));
    }
    __syncthreads();
    if (tid < 32) tab[j * 32 + tid] = tw[tid];
}

// K3: thread <-> K3R rows; popcount hq, LUT binarize, packed 120x2 matvec,
// exact integer out-stats via block-reduced global atomics.
// w-bits / lwq are read with loop-uniform addresses -> scalar loads.
__global__ __launch_bounds__(256) void k3_out(
        const u64* __restrict__ xbits, const u64* __restrict__ wbits,
        const u32* __restrict__ lwq, const u32* __restrict__ tab,
        u32* __restrict__ oqbuf, u32* __restrict__ oS, u64* __restrict__ oS2) {
    __shared__ u32 stab[DIM * 32];
    int tid = threadIdx.x;
    for (int k = tid; k < DIM * 32; k += 256) stab[k] = tab[k];
    __syncthreads();
    size_t base = (size_t)blockIdx.x * (256 * K3R);
    u64 p0[K3R], p1[K3R], z0[K3R], z1[K3R];
    bool hasZ[K3R];
    u32 oq[K3R];
    for (int r = 0; r < K3R; ++r) {
        const u64* rb = xbits + (base + (size_t)r * 256 + tid) * 4;
        p0[r] = rb[0]; p1[r] = rb[1]; z0[r] = rb[2]; z1[r] = rb[3];
        hasZ[r] = (z0[r] | z1[r]) != 0;
        oq[r] = 0;
    }
    for (int j = 0; j < DIM; ++j) {
        u64 q0 = wbits[j*4+0], q1 = wbits[j*4+1], y0 = wbits[j*4+2], y1 = wbits[j*4+3];
        bool hasY = (y0 | y1) != 0;        // wave-uniform (scalar branch)
        u32 lwp = lwq[j];
        const u32* trow = &stab[j * 32];
        #pragma unroll
        for (int r = 0; r < K3R; ++r) {
            u32 hq = (u32)(__popcll(p0[r] & q0) + __popcll(p1[r] & q1)) << 2;
            if (hasY)
                hq += 2u * (u32)(__popcll(p0[r] & y0) + __popcll(p1[r] & y1))
                    + (u32)(__popcll(z0[r] & y0) + __popcll(z1[r] & y1));
            if (hasZ[r])
                hq += 2u * (u32)(__popcll(z0[r] & q0) + __popcll(z1[r] & q1));
            u32 w = trow[hq >> 4];
            u32 hb2 = (w >> ((hq & 15) * 2)) & 3u;
            oq[r] += hb2 * lwp;            // low16: class0 (oq0<=240), high16: class1
        }
    }
    u32 a = 0, b = 0, c2 = 0, d2 = 0;
    for (int r = 0; r < K3R; ++r) {
        oqbuf[base + (size_t)r * 256 + tid] = oq[r];
        u32 o0 = oq[r] & 0xffffu, o1 = oq[r] >> 16;
        a += o0; b += o1; c2 += o0 * o0; d2 += o1 * o1;
    }
    for (int off = 32; off; off >>= 1) {
        a += __shfl_down(a, off, 64);  b += __shfl_down(b, off, 64);
        c2 += __shfl_down(c2, off, 64); d2 += __shfl_down(d2, off, 64);
    }
    __shared__ u32 r0_[4], r1_[4], r2_[4], r3_[4];
    int lane = tid & 63, wave = tid >> 6;
    if (lane == 0) { r0_[wave] = a; r1_[wave] = b; r2_[wave] = c2; r3_[wave] = d2; }
    __syncthreads();
    if (tid == 0) {
        atomicAdd(&oS[0], r0_[0] + r0_[1] + r0_[2] + r0_[3]);
        atomicAdd(&oS[1], r1_[0] + r1_[1] + r1_[2] + r1_[3]);
        atomicAdd(&oS2[0], (u64)(r2_[0] + r2_[1] + r2_[2] + r2_[3]));
        atomicAdd(&oS2[1], (u64)(r3_[0] + r3_[1] + r3_[2] + r3_[3]));
    }
}

// R3: finalize output BN constants (lin_b cancels through the no-affine BN)
__global__ void r3_ostats(const u32* __restrict__ oS, const u64* __restrict__ oS2,
                          float* __restrict__ fin) {
    if (threadIdx.x == 0) {
        for (int c = 0; c < 2; ++c) {
            double a  = (double)oS[c] * 0.25 / (double)BATCH;
            double e2 = (double)oS2[c] * 0.0625 / (double)BATCH;
            double vo = e2 - a * a;
            fin[c]     = (float)a;
            fin[2 + c] = (float)(1.0 / sqrt(vo + 1e-5));
        }
    }
}

// K4: normalize + 2-class log_softmax
__global__ __launch_bounds__(256) void k4_final(
        const u32* __restrict__ oqbuf, const float* __restrict__ fin,
        float* __restrict__ out) {
    size_t row = (size_t)blockIdx.x * 256 + threadIdx.x;
    u32 v = oqbuf[row];
    float o0 = ((float)(v & 0xffffu) * 0.25f - fin[0]) * fin[2];
    float o1 = ((float)(v >> 16)     * 0.25f - fin[1]) * fin[3];
    float m = fmaxf(o0, o1);
    float l0 = o0 - m, l1 = o1 - m;
    float ls = logf(expf(l0) + expf(l1));
    ((float2*)out)[row] = make_float2(l0 - ls, l1 - ls);
}

extern "C" void kernel_launch(void* const* d_in, const int* in_sizes, int n_in,
                              void* d_out, int out_size, void* d_ws, size_t ws_size,
                              hipStream_t stream) {
    const float* x  = (const float*)d_in[0];
    const float* cw = (const float*)d_in[1];
    const float* g2 = (const float*)d_in[2];
    const float* b2 = (const float*)d_in[3];
    const float* g1 = (const float*)d_in[4];
    const float* b1 = (const float*)d_in[5];
    const float* lw = (const float*)d_in[6];
    // d_in[7] (lin_b) cancels through the final no-affine batchnorm
    float* out = (float*)d_out;
    if (ws_size < (size_t)WS_TOTAL) return;   // fail loudly via poisoned d_out

    char* ws = (char*)d_ws;
    u64* xbits = (u64*)(ws + WS_XBITS);
    u64* wbits = (u64*)(ws + WS_WBITS);
    u32* hS    = (u32*)(ws + WS_HS);
    u32* hS2   = (u32*)(ws + WS_HS2);
    float* sS  = (float*)(ws + WS_SS);
    float* sS2 = (float*)(ws + WS_SS2);
    float* bn2c = (float*)(ws + WS_BN2C);
    u32* lwq   = (u32*)(ws + WS_LWQ);
    u32* tab   = (u32*)(ws + WS_TAB);
    u32* oqbuf = (u32*)(ws + WS_OQ);
    u32* oS    = (u32*)(ws + WS_OACC);
    u64* oS2   = (u64*)(ws + WS_OACC + 16);
    float* fin = (float*)(ws + WS_OACC + 32);

    kw_pack       <<<1, 128, 0, stream>>>(cw, lw, wbits, lwq, oS);
    k1_pack_hstats<<<NBLK1, 256, 0, stream>>>(x, wbits, xbits, hS, hS2);
    r1_hreduce    <<<DIM, 256, 0, stream>>>(hS, hS2, g2, b2, bn2c);
    k2_sstats     <<<NBLK1, 256, 0, stream>>>(xbits, wbits, bn2c, sS, sS2);
    r2_sreduce    <<<DIM, 256, 0, stream>>>(sS, sS2, g1, b1, bn2c, tab);
    k3_out        <<<BATCH/(256*K3R), 256, 0, stream>>>(xbits, wbits, lwq, tab, oqbuf, oS, oS2);
    r3_ostats     <<<1, 64, 0, stream>>>(oS, oS2, fin);
    k4_final      <<<BATCH/256, 256, 0, stream>>>(oqbuf, fin, out);
}

// Round 3
// 163.046 us; speedup vs baseline: 1.1897x; 1.1225x over previous
//
#include <hip/hip_runtime.h>
#include <stdint.h>
#include <math.h>

typedef unsigned long long u64;
typedef uint32_t u32;

#define BATCH   262144
#define DIM     120
#define NBLK1   2048      // K1/K2: 128 rows per block
#define NPART   4096      // partial slots per column (2 halves * 2048 blocks)

// ---------------- workspace layout (bytes) ----------------
#define WS_XBITS   0              // u64[BATCH*4]            8,388,608
#define WS_WBITS   8388608        // u64[128*4]                  4,096
#define WS_HS      8392704        // u32[120*4096]           1,966,080
#define WS_HS2     10358784       // u32[120*4096]           1,966,080
#define WS_SS      12324864       // f32[120*4096]           1,966,080
#define WS_SS2     14290944       // f32[120*4096]           1,966,080
#define WS_BN2C    16257024       // f32[256]  (c1q[j], c0[128+j])
#define WS_LWQ     16258048       // u32[128]  packed lin_w binarize
#define WS_THR     16258560       // int4[120] (dec, A, B, 0)        1,920
#define WS_OQ      16260608       // u32[BATCH]              1,048,576
#define WS_OACC    17309184       // u32 oS[2]; pad; u64 oS2[2]@+16
#define WS_TOTAL   17309248

// Pack conv_w via ballots (coalesced, 4 waves x 30 rows) in the same
// permuted bit order as the x packing: col c -> word (c&1), bit (c>>1).
// Also packs lin_w binarize and zeroes the k3 output accumulators.
__global__ __launch_bounds__(256) void kw_pack(
        const float* __restrict__ w, const float* __restrict__ lw,
        u64* __restrict__ wbits, u32* __restrict__ lwq, u32* __restrict__ oaccz) {
    int tid = threadIdx.x, lane = tid & 63, wv = tid >> 6;
    if (tid < 8) oaccz[tid] = 0;
    for (int j = wv; j < DIM; j += 4) {
        float2 v = make_float2(-1.f, -1.f);
        if (lane < 60) v = *(const float2*)(w + (size_t)j * DIM + lane * 2);
        u64 pe = __ballot(v.x > 0.f);
        u64 po = __ballot(v.y > 0.f);
        u64 ze = __ballot(v.x == 0.f);
        u64 zo = __ballot(v.y == 0.f);
        if (lane == 0) {
            wbits[j*4+0] = pe; wbits[j*4+1] = po;
            wbits[j*4+2] = ze; wbits[j*4+3] = zo;
        }
    }
    if (tid < DIM) {
        float w0 = lw[tid], w1 = lw[DIM + tid];
        u32 l0 = w0 > 0.f ? 2u : (w0 == 0.f ? 1u : 0u);
        u32 l1 = w1 > 0.f ? 2u : (w1 == 0.f ? 1u : 0u);
        lwq[tid] = l0 | (l1 << 16);
    }
}

__device__ __forceinline__ u32 hq_from_bits(u64 p0, u64 p1, u64 z0, u64 z1,
                                            u64 q0, u64 q1, u64 y0, u64 y1,
                                            bool hasY, bool hasZ) {
    u32 hq = (u32)(__popcll(p0 & q0) + __popcll(p1 & q1)) << 2;
    if (hasY)
        hq += 2u * (u32)(__popcll(p0 & y0) + __popcll(p1 & y1))
            + (u32)(__popcll(z0 & y0) + __popcll(z1 & y1));
    if (hasZ)
        hq += 2u * (u32)(__popcll(z0 & q0) + __popcll(z1 & q1));
    return hq;   // == 4 * h, exact integer in [0, 480]
}

// K1: pack x into bits (ballot), store bits to global, compute integer
// per-column sums of hq and hq^2 (exact, deterministic).
__global__ __launch_bounds__(256) void k1_pack_hstats(
        const float* __restrict__ x, const u64* __restrict__ wbits,
        u64* __restrict__ xbits, u32* __restrict__ hS, u32* __restrict__ hS2) {
    __shared__ u64 lb[128][4];
    int tid = threadIdx.x, lane = tid & 63, wave = tid >> 6;
    size_t rowbase = (size_t)blockIdx.x * 128;

    // phase A: 4 waves x 32 rows; one float2 load covers a whole 120-col row
    for (int rr = 0; rr < 32; ++rr) {
        int r = wave * 32 + rr;
        float2 v = make_float2(-1.f, -1.f);
        if (lane < 60) v = *(const float2*)(x + (rowbase + r) * (size_t)DIM + lane * 2);
        u64 pe = __ballot(v.x > 0.f);
        u64 po = __ballot(v.y > 0.f);
        u64 ze = __ballot(v.x == 0.f);
        u64 zo = __ballot(v.y == 0.f);
        if (lane == 0) { lb[r][0] = pe; lb[r][1] = po; lb[r][2] = ze; lb[r][3] = zo; }
    }
    __syncthreads();
    {   // coalesced copy of packed bits to global for later passes
        ((ulonglong2*)(xbits + (size_t)blockIdx.x * 512))[tid] =
            ((const ulonglong2*)&lb[0][0])[tid];
    }
    // phase B: thread <-> column; integer stats in registers
    int j = tid & 127, half = tid >> 7;
    if (j < DIM) {
        u64 q0 = wbits[j*4+0], q1 = wbits[j*4+1], y0 = wbits[j*4+2], y1 = wbits[j*4+3];
        bool hasY = (y0 | y1) != 0;
        u32 S = 0, S2 = 0;
        int r0 = half * 64;
        for (int r = r0; r < r0 + 64; ++r) {
            u64 z0 = lb[r][2], z1 = lb[r][3];
            u32 hq = hq_from_bits(lb[r][0], lb[r][1], z0, z1,
                                  q0, q1, y0, y1, hasY, (z0 | z1) != 0);
            S += hq; S2 += hq * hq;
        }
        int pidx = j * NPART + blockIdx.x * 2 + half;
        hS[pidx] = S; hS2[pidx] = S2;
    }
}

// R1: reduce integer h-stats -> fold BN2 into  z = fma(hq, c1q, c0)
__global__ __launch_bounds__(256) void r1_hreduce(
        const u32* __restrict__ hS, const u32* __restrict__ hS2,
        const float* __restrict__ g2, const float* __restrict__ b2,
        float* __restrict__ bn2c) {
    int j = blockIdx.x, tid = threadIdx.x;
    u32 s = 0; u64 s2 = 0;
    for (int k = tid; k < NPART; k += 256) { s += hS[j*NPART+k]; s2 += (u64)hS2[j*NPART+k]; }
    for (int off = 32; off; off >>= 1) { s += __shfl_down(s, off, 64); s2 += __shfl_down(s2, off, 64); }
    __shared__ u32 as_[4]; __shared__ u64 as2_[4];
    int lane = tid & 63, wave = tid >> 6;
    if (lane == 0) { as_[wave] = s; as2_[wave] = s2; }
    __syncthreads();
    if (tid == 0) {
        u32 S = as_[0] + as_[1] + as_[2] + as_[3];
        u64 S2 = as2_[0] + as2_[1] + as2_[2] + as2_[3];
        double m2 = (double)S * 0.25 / (double)BATCH;
        double e2 = (double)S2 * 0.0625 / (double)BATCH;
        double v2 = e2 - m2 * m2;
        float rs = (float)(1.0 / sqrt(v2 + 1e-5));
        float c1 = rs * g2[j];
        float c0 = fmaf(-(float)m2, c1, b2[j]);
        bn2c[j]       = c1 * 0.25f;   // pre-scaled for hq (=4h)
        bn2c[128 + j] = c0;
    }
}

// K2: stage bits in LDS, recompute hq, softsign stats (dual f32 accumulators)
__global__ __launch_bounds__(256) void k2_sstats(
        const u64* __restrict__ xbits, const u64* __restrict__ wbits,
        const float* __restrict__ bn2c,
        float* __restrict__ sS, float* __restrict__ sS2) {
    __shared__ u64 lb[128][4];
    int tid = threadIdx.x;
    ((ulonglong2*)&lb[0][0])[tid] =
        ((const ulonglong2*)(xbits + (size_t)blockIdx.x * 512))[tid];
    __syncthreads();
    int j = tid & 127, half = tid >> 7;
    if (j >= DIM) return;
    u64 q0 = wbits[j*4+0], q1 = wbits[j*4+1], y0 = wbits[j*4+2], y1 = wbits[j*4+3];
    bool hasY = (y0 | y1) != 0;
    float c1q = bn2c[j], c0 = bn2c[128 + j];
    float SsA = 0.f, Ss2A = 0.f, SsB = 0.f, Ss2B = 0.f;
    int r0 = half * 64;
    for (int r = r0; r < r0 + 64; r += 2) {
        u64 z0 = lb[r][2], z1 = lb[r][3];
        u32 hqa = hq_from_bits(lb[r][0], lb[r][1], z0, z1,
                               q0, q1, y0, y1, hasY, (z0 | z1) != 0);
        u64 w0 = lb[r+1][2], w1 = lb[r+1][3];
        u32 hqb = hq_from_bits(lb[r+1][0], lb[r+1][1], w0, w1,
                               q0, q1, y0, y1, hasY, (w0 | w1) != 0);
        float za = fmaf((float)hqa, c1q, c0);
        float sa = za * __builtin_amdgcn_rcpf(1.f + fabsf(za));
        SsA += sa; Ss2A = fmaf(sa, sa, Ss2A);
        float zb = fmaf((float)hqb, c1q, c0);
        float sb = zb * __builtin_amdgcn_rcpf(1.f + fabsf(zb));
        SsB += sb; Ss2B = fmaf(sb, sb, Ss2B);
    }
    int pidx = j * NPART + blockIdx.x * 2 + half;
    sS[pidx] = SsA + SsB; sS2[pidx] = Ss2A + Ss2B;
}

// R2: reduce softsign stats (f64), fold BN1, then derive the TWO integer
// thresholds per column: h1(hq) is monotone in hq, so binarize(h1(hq)) is a
// 2-step function. Evaluate all 481 hq with the exact float sequence, count
// n0/n1/n2, emit (dec, A, B): hb2 = dec ? (hq<A)+(hq<B) : (hq>=A)+(hq>=B).
__global__ __launch_bounds__(256) void r2_sreduce(
        const float* __restrict__ sS, const float* __restrict__ sS2,
        const float* __restrict__ g1, const float* __restrict__ b1,
        const float* __restrict__ bn2c, int* __restrict__ thr) {
    int j = blockIdx.x, tid = threadIdx.x;
    double s = 0.0, s2 = 0.0;
    for (int k = tid; k < NPART; k += 256) { s += (double)sS[j*NPART+k]; s2 += (double)sS2[j*NPART+k]; }
    for (int off = 32; off; off >>= 1) { s += __shfl_down(s, off, 64); s2 += __shfl_down(s2, off, 64); }
    __shared__ double ds_[4], ds2_[4];
    __shared__ float sd1, sd0;
    __shared__ u32 cnt[3];
    __shared__ u32 sfirst, slast;
    int lane = tid & 63, wave = tid >> 6;
    if (lane == 0) { ds_[wave] = s; ds2_[wave] = s2; }
    if (tid < 3) cnt[tid] = 0;
    __syncthreads();
    if (tid == 0) {
        double S = ds_[0] + ds_[1] + ds_[2] + ds_[3];
        double S2 = ds2_[0] + ds2_[1] + ds2_[2] + ds2_[3];
        double m1 = S / (double)BATCH;
        double v1 = S2 / (double)BATCH - m1 * m1;
        float rs = (float)(1.0 / sqrt(v1 + 1e-5));
        float d1 = rs * g1[j];
        float d0 = fmaf(-(float)m1, d1, b1[j]);
        sd1 = d1; sd0 = d0;
    }
    __syncthreads();
    float c1q = bn2c[j], c0 = bn2c[128 + j];
    float d1 = sd1, d0 = sd0;
    for (int hq = tid; hq < 481; hq += 256) {
        float z = fmaf((float)hq, c1q, c0);
        float sv = z * __builtin_amdgcn_rcpf(1.f + fabsf(z));
        float h1 = fmaf(sv, d1, d0);
        u32 hb2 = h1 > 0.f ? 2u : (h1 == 0.f ? 1u : 0u);
        atomicAdd(&cnt[hb2], 1u);
        if (hq == 0)   sfirst = hb2;
        if (hq == 480) slast  = hb2;
    }
    __syncthreads();
    if (tid == 0) {
        u32 n0 = cnt[0], n1 = cnt[1], n2 = cnt[2];
        int dec = (slast < sfirst) ? 1 : 0;
        int A = dec ? (int)n2 : (int)n0;
        int B = A + (int)n1;
        thr[j*4+0] = dec; thr[j*4+1] = A; thr[j*4+2] = B; thr[j*4+3] = 0;
    }
}

// K3: thread <-> row, NO LDS: popcount hq, 2-compare binarize, packed 120x2
// matvec, exact integer out-stats via block-reduced global atomics.
// w-bits / lwq / thr are loop-uniform -> scalar loads; rare zero-rows take a
// separate (divergence-coherent) full path.
__global__ __launch_bounds__(256) void k3_out(
        const u64* __restrict__ xbits, const u64* __restrict__ wbits,
        const u32* __restrict__ lwq, const int4* __restrict__ thr,
        u32* __restrict__ oqbuf, u32* __restrict__ oS, u64* __restrict__ oS2) {
    int tid = threadIdx.x;
    size_t row = (size_t)blockIdx.x * 256 + tid;
    const u64* rb = xbits + row * 4;
    u64 p0 = rb[0], p1 = rb[1], z0 = rb[2], z1 = rb[3];
    u32 oq = 0;
    if ((z0 | z1) == 0) {
        #pragma unroll 4
        for (int j = 0; j < DIM; ++j) {
            u64 q0 = wbits[j*4+0], q1 = wbits[j*4+1];
            u64 y0 = wbits[j*4+2], y1 = wbits[j*4+3];
            u32 hq = (u32)(__popcll(p0 & q0) + __popcll(p1 & q1)) << 2;
            if (y0 | y1)
                hq += 2u * (u32)(__popcll(p0 & y0) + __popcll(p1 & y1));
            int4 t = thr[j];
            u32 hb2 = t.x ? (u32)((hq < (u32)t.y) + (hq < (u32)t.z))
                          : (u32)((hq >= (u32)t.y) + (hq >= (u32)t.z));
            oq += hb2 * lwq[j];            // low16: class0, high16: class1
        }
    } else {
        for (int j = 0; j < DIM; ++j) {
            u64 q0 = wbits[j*4+0], q1 = wbits[j*4+1];
            u64 y0 = wbits[j*4+2], y1 = wbits[j*4+3];
            u32 hq = hq_from_bits(p0, p1, z0, z1, q0, q1, y0, y1,
                                  (y0 | y1) != 0, true);
            int4 t = thr[j];
            u32 hb2 = t.x ? (u32)((hq < (u32)t.y) + (hq < (u32)t.z))
                          : (u32)((hq >= (u32)t.y) + (hq >= (u32)t.z));
            oq += hb2 * lwq[j];
        }
    }
    oqbuf[row] = oq;
    u32 o0 = oq & 0xffffu, o1 = oq >> 16;
    u32 a = o0, b = o1, c2 = o0 * o0, d2 = o1 * o1;
    for (int off = 32; off; off >>= 1) {
        a += __shfl_down(a, off, 64);  b += __shfl_down(b, off, 64);
        c2 += __shfl_down(c2, off, 64); d2 += __shfl_down(d2, off, 64);
    }
    __shared__ u32 r0_[4], r1_[4], r2_[4], r3_[4];
    int lane = tid & 63, wave = tid >> 6;
    if (lane == 0) { r0_[wave] = a; r1_[wave] = b; r2_[wave] = c2; r3_[wave] = d2; }
    __syncthreads();
    if (tid == 0) {
        atomicAdd(&oS[0], r0_[0] + r0_[1] + r0_[2] + r0_[3]);
        atomicAdd(&oS[1], r1_[0] + r1_[1] + r1_[2] + r1_[3]);
        atomicAdd(&oS2[0], (u64)(r2_[0] + r2_[1] + r2_[2] + r2_[3]));
        atomicAdd(&oS2[1], (u64)(r3_[0] + r3_[1] + r3_[2] + r3_[3]));
    }
}

// K4: finalize output BN constants in-block (folds old r3; lin_b cancels
// through the no-affine BN), then normalize + 2-class log_softmax.
__global__ __launch_bounds__(256) void k4_final(
        const u32* __restrict__ oqbuf, const u32* __restrict__ oS,
        const u64* __restrict__ oS2, float* __restrict__ out) {
    __shared__ float sfin[4];
    int tid = threadIdx.x;
    if (tid < 2) {
        double a  = (double)oS[tid] * 0.25 / (double)BATCH;
        double e2 = (double)oS2[tid] * 0.0625 / (double)BATCH;
        double vo = e2 - a * a;
        sfin[tid]     = (float)a;
        sfin[2 + tid] = (float)(1.0 / sqrt(vo + 1e-5));
    }
    __syncthreads();
    size_t row = (size_t)blockIdx.x * 256 + tid;
    u32 v = oqbuf[row];
    float o0 = ((float)(v & 0xffffu) * 0.25f - sfin[0]) * sfin[2];
    float o1 = ((float)(v >> 16)     * 0.25f - sfin[1]) * sfin[3];
    float m = fmaxf(o0, o1);
    float l0 = o0 - m, l1 = o1 - m;
    float ls = logf(expf(l0) + expf(l1));
    ((float2*)out)[row] = make_float2(l0 - ls, l1 - ls);
}

extern "C" void kernel_launch(void* const* d_in, const int* in_sizes, int n_in,
                              void* d_out, int out_size, void* d_ws, size_t ws_size,
                              hipStream_t stream) {
    const float* x  = (const float*)d_in[0];
    const float* cw = (const float*)d_in[1];
    const float* g2 = (const float*)d_in[2];
    const float* b2 = (const float*)d_in[3];
    const float* g1 = (const float*)d_in[4];
    const float* b1 = (const float*)d_in[5];
    const float* lw = (const float*)d_in[6];
    // d_in[7] (lin_b) cancels through the final no-affine batchnorm
    float* out = (float*)d_out;
    if (ws_size < (size_t)WS_TOTAL) return;   // fail loudly via poisoned d_out

    char* ws = (char*)d_ws;
    u64* xbits = (u64*)(ws + WS_XBITS);
    u64* wbits = (u64*)(ws + WS_WBITS);
    u32* hS    = (u32*)(ws + WS_HS);
    u32* hS2   = (u32*)(ws + WS_HS2);
    float* sS  = (float*)(ws + WS_SS);
    float* sS2 = (float*)(ws + WS_SS2);
    float* bn2c = (float*)(ws + WS_BN2C);
    u32* lwq   = (u32*)(ws + WS_LWQ);
    int* thr   = (int*)(ws + WS_THR);
    u32* oqbuf = (u32*)(ws + WS_OQ);
    u32* oS    = (u32*)(ws + WS_OACC);
    u64* oS2   = (u64*)(ws + WS_OACC + 16);

    kw_pack       <<<1, 256, 0, stream>>>(cw, lw, wbits, lwq, oS);
    k1_pack_hstats<<<NBLK1, 256, 0, stream>>>(x, wbits, xbits, hS, hS2);
    r1_hreduce    <<<DIM, 256, 0, stream>>>(hS, hS2, g2, b2, bn2c);
    k2_sstats     <<<NBLK1, 256, 0, stream>>>(xbits, wbits, bn2c, sS, sS2);
    r2_sreduce    <<<DIM, 256, 0, stream>>>(sS, sS2, g1, b1, bn2c, thr);
    k3_out        <<<BATCH/256, 256, 0, stream>>>(xbits, wbits, lwq, (const int4*)thr, oqbuf, oS, oS2);
    k4_final      <<<BATCH/256, 256, 0, stream>>>(oqbuf, oS, oS2, out);
}